// Round 1
// baseline (2581.523 us; speedup 1.0000x reference)
//
#include <hip/hip_runtime.h>
#include <hip/hip_bf16.h>
#include <stdint.h>

// ARWKV-7 forward, MI355X. Round 0: full correct pipeline.
// Requires ws_size >= 242 MB (lifetime-overlapped layout, see kernel_launch).

#define B_   2
#define T_   1024
#define C_   2048
#define H_   32
#define BT_  (B_*T_)
#define FFN_ 8192

typedef unsigned short u16;
typedef __bf16 bf16x8 __attribute__((ext_vector_type(8)));
typedef u16 ushx8 __attribute__((ext_vector_type(8)));
typedef float floatx4 __attribute__((ext_vector_type(4)));

__device__ __forceinline__ float bf2f(u16 v) {
    unsigned int u = ((unsigned int)v) << 16;
    return __builtin_bit_cast(float, u);
}
__device__ __forceinline__ u16 f2bf(float f) {
    unsigned int u = __builtin_bit_cast(unsigned int, f);
    unsigned int lsb = (u >> 16) & 1u;
    u += 0x7fffu + lsb;                 // round-to-nearest-even
    return (u16)(u >> 16);
}

// ---------------- rmsnorm (out f32 or bf16) ----------------
__global__ __launch_bounds__(256) void rmsnorm_kernel(
    const float* __restrict__ in, const float* __restrict__ wgt,
    float* __restrict__ outf, u16* __restrict__ outb, int bf)
{
    int row = blockIdx.x;
    int tid = threadIdx.x;
    const float* xp = in + (size_t)row * C_;
    int c = tid * 8;
    float4 v0 = *(const float4*)&xp[c];
    float4 v1 = *(const float4*)&xp[c + 4];
    float ss = v0.x*v0.x + v0.y*v0.y + v0.z*v0.z + v0.w*v0.w
             + v1.x*v1.x + v1.y*v1.y + v1.z*v1.z + v1.w*v1.w;
    #pragma unroll
    for (int m = 1; m < 64; m <<= 1) ss += __shfl_xor(ss, m, 64);
    __shared__ float red[4];
    if ((tid & 63) == 0) red[tid >> 6] = ss;
    __syncthreads();
    ss = red[0] + red[1] + red[2] + red[3];
    float scale = 1.0f / sqrtf(ss / (float)C_ + 1e-6f);
    float vals[8] = {v0.x, v0.y, v0.z, v0.w, v1.x, v1.y, v1.z, v1.w};
    size_t base = (size_t)row * C_ + c;
    if (bf) {
        #pragma unroll
        for (int j = 0; j < 8; j++) outb[base + j] = f2bf(wgt[c + j] * vals[j] * scale);
    } else {
        #pragma unroll
        for (int j = 0; j < 8; j++) outf[base + j] = wgt[c + j] * vals[j] * scale;
    }
}

// ---------------- token-shift mix: 6 bf16 outputs ----------------
__global__ __launch_bounds__(256) void mix_kernel(
    const float* __restrict__ xn, const float* __restrict__ x_prev,
    const float* __restrict__ mr, const float* __restrict__ mw,
    const float* __restrict__ mk, const float* __restrict__ mv,
    const float* __restrict__ ma, const float* __restrict__ mg,
    u16* __restrict__ oxr, u16* __restrict__ oxw, u16* __restrict__ oxk,
    u16* __restrict__ oxv, u16* __restrict__ oxa, u16* __restrict__ oxg)
{
    int row = blockIdx.x;
    int b = row / T_;
    int t = row - b * T_;
    int c = threadIdx.x * 8;
    size_t base = (size_t)row * C_ + c;
    const float* prev = (t == 0) ? (x_prev + (size_t)b * C_ + c) : (xn + base - C_);
    #pragma unroll
    for (int j = 0; j < 8; j++) {
        float xc = xn[base + j];
        float sx = prev[j] - xc;
        int cc = c + j;
        oxr[base + j] = f2bf(xc + sx * mr[cc]);
        oxw[base + j] = f2bf(xc + sx * mw[cc]);
        oxk[base + j] = f2bf(xc + sx * mk[cc]);
        oxv[base + j] = f2bf(xc + sx * mv[cc]);
        oxa[base + j] = f2bf(xc + sx * ma[cc]);
        oxg[base + j] = f2bf(xc + sx * mg[cc]);
    }
}

// ---------------- f32 -> bf16 convert ----------------
__global__ __launch_bounds__(256) void cvt_bf16_kernel(
    const float* __restrict__ in, u16* __restrict__ out, long n)
{
    long i = ((long)blockIdx.x * 256 + threadIdx.x) * 4;
    if (i + 3 >= n) return;
    float4 v = *(const float4*)&in[i];
    out[i]     = f2bf(v.x);
    out[i + 1] = f2bf(v.y);
    out[i + 2] = f2bf(v.z);
    out[i + 3] = f2bf(v.w);
}

// ---------------- transpose [rows_in, cols_in] f32 -> [cols_in, rows_in] bf16 ----------------
__global__ __launch_bounds__(256) void transpose_kernel(
    const float* __restrict__ in, u16* __restrict__ out, int rows_in, int cols_in)
{
    long idx = (long)blockIdx.x * 256 + threadIdx.x;
    long total = (long)rows_in * cols_in;
    if (idx >= total) return;
    long o = idx / rows_in;
    long i = idx - o * rows_in;
    out[idx] = f2bf(in[i * (long)cols_in + o]);
}

// ---------------- skinny GEMM: C[M,D] = act(Xbf16[M,K] @ Wf32[K,D]) -> bf16 ----------------
// act: 0 = tanh, 1 = none, 2 = sigmoid.  lanes = D outputs; block covers 256/D rows.
__global__ __launch_bounds__(256) void skinny_gemm_kernel(
    const u16* __restrict__ X, const float* __restrict__ W, u16* __restrict__ Cb,
    int M, int K, int D, int act)
{
    int o = threadIdx.x % D;
    int slot = threadIdx.x / D;
    int R = 256 / D;
    int row = blockIdx.x * R + slot;
    if (row >= M) return;
    const u16* xp = X + (size_t)row * K;
    float acc = 0.f;
    for (int c = 0; c < K; c += 2) {
        unsigned int x2v = *(const unsigned int*)&xp[c];
        float x0 = bf2f((u16)(x2v & 0xffffu));
        float x1 = bf2f((u16)(x2v >> 16));
        float wv0 = W[(size_t)c * D + o];
        float wv1 = W[(size_t)(c + 1) * D + o];
        acc += x0 * wv0 + x1 * wv1;
    }
    float r;
    if (act == 0) r = tanhf(acc);
    else if (act == 2) r = 1.f / (1.f + expf(-acc));
    else r = acc;
    Cb[(size_t)row * D + o] = f2bf(r);
}

// ---------------- main MFMA GEMM: C[M,N] = A[M,K]bf16 @ W[N,K]bf16^T ----------------
// 128x128 tile, BK=32, 4 waves (2x2), each wave 4x4 tiles of mfma_f32_16x16x32_bf16.
// Epilogue modes: 0: Cf=acc; 1: Cb=bf16(acc*bf2f(Ob[idx])); 2: Cb=bf16(silu(acc));
//                 3: Cf=acc+Of[idx].
#define LSTR 40
__global__ __launch_bounds__(256, 2) void gemm_kernel(
    const u16* __restrict__ A, const u16* __restrict__ W,
    float* __restrict__ Cf, u16* __restrict__ Cb,
    const float* __restrict__ Of, const u16* __restrict__ Ob,
    int M, int N, int K, int mode)
{
    __shared__ u16 As[128 * LSTR];
    __shared__ u16 Ws[128 * LSTR];
    const int tid = threadIdx.x;
    const int bm = blockIdx.y, bn = blockIdx.x;
    const int row0 = bm * 128, col0 = bn * 128;
    const int wave = tid >> 6, lane = tid & 63;
    const int wr = wave >> 1, wc = wave & 1;
    const int q = lane >> 4, l16 = lane & 15;

    floatx4 acc[4][4];
    #pragma unroll
    for (int i = 0; i < 4; i++)
        #pragma unroll
        for (int j = 0; j < 4; j++) acc[i][j] = (floatx4){0.f, 0.f, 0.f, 0.f};

    const int r0 = tid >> 2;          // 0..63
    const int cb0 = (tid & 3) * 8;    // 0,8,16,24

    for (int k0 = 0; k0 < K; k0 += 32) {
        __syncthreads();
        {
            ushx8 va0 = *(const ushx8*)&A[(size_t)(row0 + r0) * K + k0 + cb0];
            ushx8 vw0 = *(const ushx8*)&W[(size_t)(col0 + r0) * K + k0 + cb0];
            ushx8 va1 = *(const ushx8*)&A[(size_t)(row0 + r0 + 64) * K + k0 + cb0];
            ushx8 vw1 = *(const ushx8*)&W[(size_t)(col0 + r0 + 64) * K + k0 + cb0];
            *(ushx8*)&As[r0 * LSTR + cb0] = va0;
            *(ushx8*)&Ws[r0 * LSTR + cb0] = vw0;
            *(ushx8*)&As[(r0 + 64) * LSTR + cb0] = va1;
            *(ushx8*)&Ws[(r0 + 64) * LSTR + cb0] = vw1;
        }
        __syncthreads();
        bf16x8 af[4], wf[4];
        #pragma unroll
        for (int im = 0; im < 4; im++) {
            int r = wr * 64 + im * 16 + l16;
            af[im] = __builtin_bit_cast(bf16x8, *(const ushx8*)&As[r * LSTR + q * 8]);
        }
        #pragma unroll
        for (int in_ = 0; in_ < 4; in_++) {
            int r = wc * 64 + in_ * 16 + l16;
            wf[in_] = __builtin_bit_cast(bf16x8, *(const ushx8*)&Ws[r * LSTR + q * 8]);
        }
        #pragma unroll
        for (int im = 0; im < 4; im++)
            #pragma unroll
            for (int in_ = 0; in_ < 4; in_++)
                acc[im][in_] = __builtin_amdgcn_mfma_f32_16x16x32_bf16(
                    af[im], wf[in_], acc[im][in_], 0, 0, 0);
    }

    #pragma unroll
    for (int im = 0; im < 4; im++) {
        #pragma unroll
        for (int in_ = 0; in_ < 4; in_++) {
            #pragma unroll
            for (int rg = 0; rg < 4; rg++) {
                int row = row0 + wr * 64 + im * 16 + q * 4 + rg;
                int col = col0 + wc * 64 + in_ * 16 + l16;
                if (row < M && col < N) {
                    size_t idx = (size_t)row * N + col;
                    float v = acc[im][in_][rg];
                    switch (mode) {
                        case 0: Cf[idx] = v; break;
                        case 1: Cb[idx] = f2bf(v * bf2f(Ob[idx])); break;
                        case 2: { float s = v / (1.f + expf(-v)); Cb[idx] = f2bf(s); } break;
                        case 3: Cf[idx] = v + Of[idx]; break;
                    }
                }
            }
        }
    }
}

// ---------------- decay: d = exp(-exp(-softplus(-(w0+z)) - 0.5)), in place ----------------
__global__ __launch_bounds__(256) void decay_kernel(
    float* __restrict__ z, const float* __restrict__ w0)
{
    long i = (long)blockIdx.x * 256 + threadIdx.x;
    int c = (int)(i & (C_ - 1));
    float zp = w0[c] + z[i];
    float xneg = -zp;
    float sp = (xneg > 20.f) ? xneg : log1pf(expf(xneg));
    float wpre = -sp - 0.5f;
    z[i] = expf(-expf(wpre));
}

// ---------------- a = sigmoid(a0 + z), in place ----------------
__global__ __launch_bounds__(256) void siga_kernel(
    float* __restrict__ z, const float* __restrict__ a0)
{
    long i = (long)blockIdx.x * 256 + threadIdx.x;
    int c = (int)(i & (C_ - 1));
    z[i] = 1.f / (1.f + expf(-(a0[c] + z[i])));
}

// ---------------- kk = normalize(k*k_k) per head; k <- k*(1+(a-1)*k_a) in place ----------------
__global__ __launch_bounds__(256) void kknorm_kernel(
    float* __restrict__ k, const float* __restrict__ a,
    const float* __restrict__ k_k, const float* __restrict__ k_a,
    float* __restrict__ kk)
{
    int row = blockIdx.x;
    int c = threadIdx.x * 8;           // 8 threads per 64-wide head
    size_t base = (size_t)row * C_ + c;
    float kl[8], kkl[8];
    float ss = 0.f;
    #pragma unroll
    for (int j = 0; j < 8; j++) {
        kl[j] = k[base + j];
        float t = kl[j] * k_k[c + j];
        kkl[j] = t;
        ss += t * t;
    }
    ss += __shfl_xor(ss, 1, 64);
    ss += __shfl_xor(ss, 2, 64);
    ss += __shfl_xor(ss, 4, 64);
    float inv = 1.f / fmaxf(sqrtf(ss), 1e-12f);
    #pragma unroll
    for (int j = 0; j < 8; j++) {
        kk[base + j] = kkl[j] * inv;
        float av = a[base + j];
        k[base + j] = kl[j] * (1.f + (av - 1.f) * k_a[c + j]);
    }
}

// ---------------- RWKV-7 scan ----------------
// Row-independent recurrence. Block = 256 threads = 16 rows x 16 col-groups (4 cols each).
// Grid = 64 (b,h) x 4 row-blocks = 256 blocks. Vectors staged 16 timesteps/batch in LDS.
#define SB 16
__global__ __launch_bounds__(256) void scan_kernel(
    const float* __restrict__ rp, const float* __restrict__ dp,
    const float* __restrict__ kp, const float* __restrict__ kkp,
    const float* __restrict__ ap, const float* __restrict__ vp,
    const float* __restrict__ st0, float* __restrict__ xx)
{
    int blk = blockIdx.x;
    int bh = blk >> 2, vblk = blk & 3;
    int b = bh >> 5, h = bh & 31;
    int tid = threadIdx.x;
    int vloc = tid >> 4, kg = tid & 15, c0 = kg * 4;
    int vrow = vblk * 16 + vloc;
    float S0, S1, S2, S3;
    {
        const float* sp = st0 + ((size_t)bh * 64 + vrow) * 64 + c0;
        S0 = sp[0]; S1 = sp[1]; S2 = sp[2]; S3 = sp[3];
    }
    __shared__ float Rs[SB][64], Ds[SB][64], Ks[SB][64], KKs[SB][64], As[SB][64], Vs[SB][64];
    int sidx = (tid * 4) >> 6;
    int nidx = (tid * 4) & 63;
    for (int t0 = 0; t0 < T_; t0 += SB) {
        __syncthreads();
        size_t g = ((size_t)b * T_ + t0 + sidx) * C_ + h * 64 + nidx;
        *(float4*)&Rs[sidx][nidx]  = *(const float4*)&rp[g];
        *(float4*)&Ds[sidx][nidx]  = *(const float4*)&dp[g];
        *(float4*)&Ks[sidx][nidx]  = *(const float4*)&kp[g];
        *(float4*)&KKs[sidx][nidx] = *(const float4*)&kkp[g];
        *(float4*)&As[sidx][nidx]  = *(const float4*)&ap[g];
        *(float4*)&Vs[sidx][nidx]  = *(const float4*)&vp[g];
        __syncthreads();
        for (int s = 0; s < SB; s++) {
            float4 dv  = *(const float4*)&Ds[s][c0];
            float4 kv  = *(const float4*)&Ks[s][c0];
            float4 kkv = *(const float4*)&KKs[s][c0];
            float4 av  = *(const float4*)&As[s][c0];
            float4 rv  = *(const float4*)&Rs[s][c0];
            float vt = Vs[s][vrow];
            // sa = S . aa,  aa = -kk
            float sa = -(S0 * kkv.x + S1 * kkv.y + S2 * kkv.z + S3 * kkv.w);
            sa += __shfl_xor(sa, 1, 64);
            sa += __shfl_xor(sa, 2, 64);
            sa += __shfl_xor(sa, 4, 64);
            sa += __shfl_xor(sa, 8, 64);
            // S = S*d + sa*(kk*a) + vt*k ;  o = S . r
            S0 = S0 * dv.x + sa * (kkv.x * av.x) + vt * kv.x;
            S1 = S1 * dv.y + sa * (kkv.y * av.y) + vt * kv.y;
            S2 = S2 * dv.z + sa * (kkv.z * av.z) + vt * kv.z;
            S3 = S3 * dv.w + sa * (kkv.w * av.w) + vt * kv.w;
            float o = S0 * rv.x + S1 * rv.y + S2 * rv.z + S3 * rv.w;
            o += __shfl_xor(o, 1, 64);
            o += __shfl_xor(o, 2, 64);
            o += __shfl_xor(o, 4, 64);
            o += __shfl_xor(o, 8, 64);
            if (kg == 0)
                xx[((size_t)b * T_ + t0 + s) * C_ + h * 64 + vrow] = o;
        }
    }
}

// ---------------- bonus + gate: y = (xx + (sum_head r*k*r_k)*v) * g -> bf16 ----------------
__global__ __launch_bounds__(256) void ygate_kernel(
    const float* __restrict__ xx, const float* __restrict__ r,
    const float* __restrict__ k, const float* __restrict__ r_k,
    const float* __restrict__ v, const float* __restrict__ g,
    u16* __restrict__ y)
{
    int row = blockIdx.x;
    int c = threadIdx.x * 8;
    size_t base = (size_t)row * C_ + c;
    float bsum = 0.f;
    #pragma unroll
    for (int j = 0; j < 8; j++) bsum += r[base + j] * k[base + j] * r_k[c + j];
    bsum += __shfl_xor(bsum, 1, 64);
    bsum += __shfl_xor(bsum, 2, 64);
    bsum += __shfl_xor(bsum, 4, 64);
    #pragma unroll
    for (int j = 0; j < 8; j++) {
        float yv = (xx[base + j] + bsum * v[base + j]) * g[base + j];
        y[base + j] = f2bf(yv);
    }
}

extern "C" void kernel_launch(void* const* d_in, const int* in_sizes, int n_in,
                              void* d_out, int out_size, void* d_ws, size_t ws_size,
                              hipStream_t stream)
{
    const float* x      = (const float*)d_in[0];
    const float* x_prev = (const float*)d_in[1];
    const float* state  = (const float*)d_in[2];
    const float* ln1_w  = (const float*)d_in[3];
    const float* ln2_w  = (const float*)d_in[4];
    const float* x_r = (const float*)d_in[5];
    const float* x_w = (const float*)d_in[6];
    const float* x_k = (const float*)d_in[7];
    const float* x_v = (const float*)d_in[8];
    const float* x_a = (const float*)d_in[9];
    const float* x_g = (const float*)d_in[10];
    const float* w0 = (const float*)d_in[11];
    const float* w1 = (const float*)d_in[12];
    const float* w2 = (const float*)d_in[13];
    const float* a0 = (const float*)d_in[14];
    const float* a1 = (const float*)d_in[15];
    const float* a2 = (const float*)d_in[16];
    const float* g1 = (const float*)d_in[17];
    const float* g2 = (const float*)d_in[18];
    const float* k_k = (const float*)d_in[19];
    const float* k_a = (const float*)d_in[20];
    const float* r_k = (const float*)d_in[21];
    const float* Rw = (const float*)d_in[22];
    const float* Kw = (const float*)d_in[23];
    const float* Vw = (const float*)d_in[24];
    const float* Ow = (const float*)d_in[25];
    const float* gate_w = (const float*)d_in[26];
    const float* up_w   = (const float*)d_in[27];
    const float* down_w = (const float*)d_in[28];
    float* out = (float*)d_out;

    const size_t MBc = 1024ull * 1024ull;
    char* ws = (char*)d_ws;
    // --- lifetime-overlapped layout (242 MB total) ---
    u16*  xr_b = (u16*)(ws + 0 * MBc);
    u16*  xw_b = (u16*)(ws + 8 * MBc);
    u16*  xk_b = (u16*)(ws + 16 * MBc);
    u16*  xv_b = (u16*)(ws + 24 * MBc);
    u16*  xa_b = (u16*)(ws + 32 * MBc);
    u16*  xg_b = (u16*)(ws + 40 * MBc);
    float* xn  = (float*)(ws + 48 * MBc);   // dead before rb written
    float* rb  = (float*)(ws + 48 * MBc);
    float* kb  = (float*)(ws + 64 * MBc);
    float* vb  = (float*)(ws + 80 * MBc);
    float* db  = (float*)(ws + 96 * MBc);
    float* ab  = (float*)(ws + 112 * MBc);
    float* gb  = (float*)(ws + 128 * MBc);
    float* kkb = (float*)(ws + 144 * MBc);
    float* xxb = (float*)(ws + 160 * MBc);
    u16*  yb   = (u16*)(ws + 176 * MBc);
    float* x2  = (float*)(ws + 184 * MBc);
    u16*  xn2b = (u16*)(ws + 200 * MBc);
    u16*  Rb   = (u16*)(ws + 208 * MBc);
    u16*  Kb   = (u16*)(ws + 216 * MBc);
    u16*  Vb   = (u16*)(ws + 224 * MBc);
    u16*  Owb  = (u16*)(ws + 232 * MBc);
    // late-phase reuse (mix planes + r/k/v/d/a/g/kk are all dead by then):
    u16*  gateb = (u16*)(ws + 0 * MBc);
    u16*  upb   = (u16*)(ws + 32 * MBc);
    u16*  downb = (u16*)(ws + 64 * MBc);
    u16*  gfb   = (u16*)(ws + 96 * MBc);
    u16*  hb    = (u16*)(ws + 128 * MBc);
    u16*  w2T = (u16*)(ws + 240 * MBc);
    u16*  a2T = (u16*)(ws + 240 * MBc + 256 * 1024);
    u16*  g2T = (u16*)(ws + 240 * MBc + 512 * 1024);
    u16*  t1b = (u16*)(ws + 241 * MBc);
    u16*  t2b = (u16*)(ws + 241 * MBc + 256 * 1024);
    u16*  t3b = (u16*)(ws + 241 * MBc + 512 * 1024);

    const long cc = (long)C_ * C_;
    const long fc = (long)FFN_ * C_;

    // 1) ln1 + token-shift mixes
    rmsnorm_kernel<<<BT_, 256, 0, stream>>>(x, ln1_w, xn, nullptr, 0);
    mix_kernel<<<BT_, 256, 0, stream>>>(xn, x_prev, x_r, x_w, x_k, x_v, x_a, x_g,
                                        xr_b, xw_b, xk_b, xv_b, xa_b, xg_b);
    // 2) weight conversions (R/K/V/O) + small transposes
    cvt_bf16_kernel<<<cc / 1024, 256, 0, stream>>>(Rw, Rb, cc);
    cvt_bf16_kernel<<<cc / 1024, 256, 0, stream>>>(Kw, Kb, cc);
    cvt_bf16_kernel<<<cc / 1024, 256, 0, stream>>>(Vw, Vb, cc);
    cvt_bf16_kernel<<<cc / 1024, 256, 0, stream>>>(Ow, Owb, cc);
    transpose_kernel<<<(64 * C_ + 255) / 256, 256, 0, stream>>>(w2, w2T, 64, C_);
    transpose_kernel<<<(64 * C_ + 255) / 256, 256, 0, stream>>>(a2, a2T, 64, C_);
    transpose_kernel<<<(128 * C_ + 255) / 256, 256, 0, stream>>>(g2, g2T, 128, C_);
    // 3) r/k/v projections
    gemm_kernel<<<dim3(16, 16), 256, 0, stream>>>(xr_b, Rb, rb, nullptr, nullptr, nullptr, BT_, C_, C_, 0);
    gemm_kernel<<<dim3(16, 16), 256, 0, stream>>>(xk_b, Kb, kb, nullptr, nullptr, nullptr, BT_, C_, C_, 0);
    gemm_kernel<<<dim3(16, 16), 256, 0, stream>>>(xv_b, Vb, vb, nullptr, nullptr, nullptr, BT_, C_, C_, 0);
    // 4) decay path: d = exp(-exp(-softplus(-(w0 + tanh(xw@w1)@w2)) - 0.5))
    skinny_gemm_kernel<<<BT_ / 4, 256, 0, stream>>>(xw_b, w1, t1b, BT_, C_, 64, 0);
    gemm_kernel<<<dim3(16, 16), 256, 0, stream>>>(t1b, w2T, db, nullptr, nullptr, nullptr, BT_, C_, 64, 0);
    decay_kernel<<<(BT_ * C_) / 256, 256, 0, stream>>>(db, w0);
    // 5) a path: a = sigmoid(a0 + (xa@a1)@a2)
    skinny_gemm_kernel<<<BT_ / 4, 256, 0, stream>>>(xa_b, a1, t2b, BT_, C_, 64, 1);
    gemm_kernel<<<dim3(16, 16), 256, 0, stream>>>(t2b, a2T, ab, nullptr, nullptr, nullptr, BT_, C_, 64, 0);
    siga_kernel<<<(BT_ * C_) / 256, 256, 0, stream>>>(ab, a0);
    // 6) g path: g = sigmoid(xg@g1)@g2
    skinny_gemm_kernel<<<BT_ / 2, 256, 0, stream>>>(xg_b, g1, t3b, BT_, C_, 128, 2);
    gemm_kernel<<<dim3(16, 16), 256, 0, stream>>>(t3b, g2T, gb, nullptr, nullptr, nullptr, BT_, C_, 128, 0);
    // 7) kk normalize + k adjust
    kknorm_kernel<<<BT_, 256, 0, stream>>>(kb, ab, k_k, k_a, kkb);
    // 8) RWKV-7 scan
    scan_kernel<<<256, 256, 0, stream>>>(rb, db, kb, kkb, ab, vb, state, xxb);
    // 9) bonus + gate, O-proj with fused residual: x2 = x + ((xx+bonus)*g)@O^T
    ygate_kernel<<<BT_, 256, 0, stream>>>(xxb, rb, kb, r_k, vb, gb, yb);
    gemm_kernel<<<dim3(16, 16), 256, 0, stream>>>(yb, Owb, x2, nullptr, x, nullptr, BT_, C_, C_, 3);
    // 10) MLP weights (regions now free), ln2, SwiGLU MLP with fused residual into d_out
    cvt_bf16_kernel<<<fc / 1024, 256, 0, stream>>>(gate_w, gateb, fc);
    cvt_bf16_kernel<<<fc / 1024, 256, 0, stream>>>(up_w, upb, fc);
    cvt_bf16_kernel<<<fc / 1024, 256, 0, stream>>>(down_w, downb, fc);
    rmsnorm_kernel<<<BT_, 256, 0, stream>>>(x2, ln2_w, nullptr, xn2b, 1);
    gemm_kernel<<<dim3(64, 16), 256, 0, stream>>>(xn2b, gateb, nullptr, gfb, nullptr, nullptr, BT_, FFN_, C_, 2);
    gemm_kernel<<<dim3(64, 16), 256, 0, stream>>>(xn2b, upb, nullptr, hb, nullptr, gfb, BT_, FFN_, C_, 1);
    gemm_kernel<<<dim3(16, 16), 256, 0, stream>>>(hb, downb, out, nullptr, x2, nullptr, BT_, C_, FFN_, 3);
}

// Round 2
// 1603.967 us; speedup vs baseline: 1.6095x; 1.6095x over previous
//
#include <hip/hip_runtime.h>
#include <hip/hip_bf16.h>
#include <stdint.h>

// ARWKV-7 forward, MI355X. Round 1: replace latency-bound skinny GEMMs
// (3 x 410us = 48% of runtime) with MFMA BN=64 GEMM variant.

#define B_   2
#define T_   1024
#define C_   2048
#define H_   32
#define BT_  (B_*T_)
#define FFN_ 8192

typedef unsigned short u16;
typedef __bf16 bf16x8 __attribute__((ext_vector_type(8)));
typedef u16 ushx8 __attribute__((ext_vector_type(8)));
typedef float floatx4 __attribute__((ext_vector_type(4)));

__device__ __forceinline__ float bf2f(u16 v) {
    unsigned int u = ((unsigned int)v) << 16;
    return __builtin_bit_cast(float, u);
}
__device__ __forceinline__ u16 f2bf(float f) {
    unsigned int u = __builtin_bit_cast(unsigned int, f);
    unsigned int lsb = (u >> 16) & 1u;
    u += 0x7fffu + lsb;                 // round-to-nearest-even
    return (u16)(u >> 16);
}

// ---------------- rmsnorm (out f32 or bf16) ----------------
__global__ __launch_bounds__(256) void rmsnorm_kernel(
    const float* __restrict__ in, const float* __restrict__ wgt,
    float* __restrict__ outf, u16* __restrict__ outb, int bf)
{
    int row = blockIdx.x;
    int tid = threadIdx.x;
    const float* xp = in + (size_t)row * C_;
    int c = tid * 8;
    float4 v0 = *(const float4*)&xp[c];
    float4 v1 = *(const float4*)&xp[c + 4];
    float ss = v0.x*v0.x + v0.y*v0.y + v0.z*v0.z + v0.w*v0.w
             + v1.x*v1.x + v1.y*v1.y + v1.z*v1.z + v1.w*v1.w;
    #pragma unroll
    for (int m = 1; m < 64; m <<= 1) ss += __shfl_xor(ss, m, 64);
    __shared__ float red[4];
    if ((tid & 63) == 0) red[tid >> 6] = ss;
    __syncthreads();
    ss = red[0] + red[1] + red[2] + red[3];
    float scale = 1.0f / sqrtf(ss / (float)C_ + 1e-6f);
    float vals[8] = {v0.x, v0.y, v0.z, v0.w, v1.x, v1.y, v1.z, v1.w};
    size_t base = (size_t)row * C_ + c;
    if (bf) {
        #pragma unroll
        for (int j = 0; j < 8; j++) outb[base + j] = f2bf(wgt[c + j] * vals[j] * scale);
    } else {
        #pragma unroll
        for (int j = 0; j < 8; j++) outf[base + j] = wgt[c + j] * vals[j] * scale;
    }
}

// ---------------- token-shift mix: 6 bf16 outputs ----------------
__global__ __launch_bounds__(256) void mix_kernel(
    const float* __restrict__ xn, const float* __restrict__ x_prev,
    const float* __restrict__ mr, const float* __restrict__ mw,
    const float* __restrict__ mk, const float* __restrict__ mv,
    const float* __restrict__ ma, const float* __restrict__ mg,
    u16* __restrict__ oxr, u16* __restrict__ oxw, u16* __restrict__ oxk,
    u16* __restrict__ oxv, u16* __restrict__ oxa, u16* __restrict__ oxg)
{
    int row = blockIdx.x;
    int b = row / T_;
    int t = row - b * T_;
    int c = threadIdx.x * 8;
    size_t base = (size_t)row * C_ + c;
    const float* prev = (t == 0) ? (x_prev + (size_t)b * C_ + c) : (xn + base - C_);
    #pragma unroll
    for (int j = 0; j < 8; j++) {
        float xc = xn[base + j];
        float sx = prev[j] - xc;
        int cc = c + j;
        oxr[base + j] = f2bf(xc + sx * mr[cc]);
        oxw[base + j] = f2bf(xc + sx * mw[cc]);
        oxk[base + j] = f2bf(xc + sx * mk[cc]);
        oxv[base + j] = f2bf(xc + sx * mv[cc]);
        oxa[base + j] = f2bf(xc + sx * ma[cc]);
        oxg[base + j] = f2bf(xc + sx * mg[cc]);
    }
}

// ---------------- f32 -> bf16 convert ----------------
__global__ __launch_bounds__(256) void cvt_bf16_kernel(
    const float* __restrict__ in, u16* __restrict__ out, long n)
{
    long i = ((long)blockIdx.x * 256 + threadIdx.x) * 4;
    if (i + 3 >= n) return;
    float4 v = *(const float4*)&in[i];
    out[i]     = f2bf(v.x);
    out[i + 1] = f2bf(v.y);
    out[i + 2] = f2bf(v.z);
    out[i + 3] = f2bf(v.w);
}

// ---------------- transpose [rows_in, cols_in] f32 -> [cols_in, rows_in] bf16 ----------------
__global__ __launch_bounds__(256) void transpose_kernel(
    const float* __restrict__ in, u16* __restrict__ out, int rows_in, int cols_in)
{
    long idx = (long)blockIdx.x * 256 + threadIdx.x;
    long total = (long)rows_in * cols_in;
    if (idx >= total) return;
    long o = idx / rows_in;
    long i = idx - o * rows_in;
    out[idx] = f2bf(in[i * (long)cols_in + o]);
}

// ---------------- main MFMA GEMM: C[M,N] = A[M,K]bf16 @ W[N,K]bf16^T ----------------
// BMxBN tile (BM=128, BN=128 or 64), BK=32, 4 waves (2x2), wave computes
// 4 x (BN/32) tiles of mfma_f32_16x16x32_bf16.
// Epilogue modes: 0: Cf=acc; 1: Cb=bf16(acc*bf2f(Ob[idx])); 2: Cb=bf16(silu(acc));
//   3: Cf=acc+Of[idx]; 4: Cb=bf16(tanh(acc)); 5: Cb=bf16(sigmoid(acc)); 6: Cb=bf16(acc).
#define LSTR 40
template<int BN>
__global__ __launch_bounds__(256, 2) void gemm_kernel(
    const u16* __restrict__ A, const u16* __restrict__ W,
    float* __restrict__ Cf, u16* __restrict__ Cb,
    const float* __restrict__ Of, const u16* __restrict__ Ob,
    int M, int N, int K, int mode)
{
    constexpr int IN = BN / 32;        // tiles per wave in N: 4 (BN=128) or 2 (BN=64)
    __shared__ u16 As[128 * LSTR];
    __shared__ u16 Ws[BN * LSTR];
    const int tid = threadIdx.x;
    const int bm = blockIdx.y, bn = blockIdx.x;
    const int row0 = bm * 128, col0 = bn * BN;
    const int wave = tid >> 6, lane = tid & 63;
    const int wr = wave >> 1, wc = wave & 1;
    const int q = lane >> 4, l16 = lane & 15;

    floatx4 acc[4][IN];
    #pragma unroll
    for (int i = 0; i < 4; i++)
        #pragma unroll
        for (int j = 0; j < IN; j++) acc[i][j] = (floatx4){0.f, 0.f, 0.f, 0.f};

    const int r0 = tid >> 2;          // 0..63
    const int cb0 = (tid & 3) * 8;    // 0,8,16,24

    for (int k0 = 0; k0 < K; k0 += 32) {
        __syncthreads();
        {
            ushx8 va0 = *(const ushx8*)&A[(size_t)(row0 + r0) * K + k0 + cb0];
            ushx8 vw0 = *(const ushx8*)&W[(size_t)(col0 + r0) * K + k0 + cb0];
            ushx8 va1 = *(const ushx8*)&A[(size_t)(row0 + r0 + 64) * K + k0 + cb0];
            *(ushx8*)&As[r0 * LSTR + cb0] = va0;
            *(ushx8*)&Ws[r0 * LSTR + cb0] = vw0;
            *(ushx8*)&As[(r0 + 64) * LSTR + cb0] = va1;
            if (BN == 128) {
                ushx8 vw1 = *(const ushx8*)&W[(size_t)(col0 + r0 + 64) * K + k0 + cb0];
                *(ushx8*)&Ws[(r0 + 64) * LSTR + cb0] = vw1;
            }
        }
        __syncthreads();
        bf16x8 af[4], wf[IN];
        #pragma unroll
        for (int im = 0; im < 4; im++) {
            int r = wr * 64 + im * 16 + l16;
            af[im] = __builtin_bit_cast(bf16x8, *(const ushx8*)&As[r * LSTR + q * 8]);
        }
        #pragma unroll
        for (int in_ = 0; in_ < IN; in_++) {
            int r = wc * (BN / 2) + in_ * 16 + l16;
            wf[in_] = __builtin_bit_cast(bf16x8, *(const ushx8*)&Ws[r * LSTR + q * 8]);
        }
        #pragma unroll
        for (int im = 0; im < 4; im++)
            #pragma unroll
            for (int in_ = 0; in_ < IN; in_++)
                acc[im][in_] = __builtin_amdgcn_mfma_f32_16x16x32_bf16(
                    af[im], wf[in_], acc[im][in_], 0, 0, 0);
    }

    #pragma unroll
    for (int im = 0; im < 4; im++) {
        #pragma unroll
        for (int in_ = 0; in_ < IN; in_++) {
            #pragma unroll
            for (int rg = 0; rg < 4; rg++) {
                int row = row0 + wr * 64 + im * 16 + q * 4 + rg;
                int col = col0 + wc * (BN / 2) + in_ * 16 + l16;
                if (row < M && col < N) {
                    size_t idx = (size_t)row * N + col;
                    float v = acc[im][in_][rg];
                    switch (mode) {
                        case 0: Cf[idx] = v; break;
                        case 1: Cb[idx] = f2bf(v * bf2f(Ob[idx])); break;
                        case 2: { float s = v / (1.f + expf(-v)); Cb[idx] = f2bf(s); } break;
                        case 3: Cf[idx] = v + Of[idx]; break;
                        case 4: Cb[idx] = f2bf(tanhf(v)); break;
                        case 5: Cb[idx] = f2bf(1.f / (1.f + expf(-v))); break;
                        case 6: Cb[idx] = f2bf(v); break;
                    }
                }
            }
        }
    }
}

// ---------------- decay: d = exp(-exp(-softplus(-(w0+z)) - 0.5)), in place ----------------
__global__ __launch_bounds__(256) void decay_kernel(
    float* __restrict__ z, const float* __restrict__ w0)
{
    long i = (long)blockIdx.x * 256 + threadIdx.x;
    int c = (int)(i & (C_ - 1));
    float zp = w0[c] + z[i];
    float xneg = -zp;
    float sp = (xneg > 20.f) ? xneg : log1pf(expf(xneg));
    float wpre = -sp - 0.5f;
    z[i] = expf(-expf(wpre));
}

// ---------------- a = sigmoid(a0 + z), in place ----------------
__global__ __launch_bounds__(256) void siga_kernel(
    float* __restrict__ z, const float* __restrict__ a0)
{
    long i = (long)blockIdx.x * 256 + threadIdx.x;
    int c = (int)(i & (C_ - 1));
    z[i] = 1.f / (1.f + expf(-(a0[c] + z[i])));
}

// ---------------- kk = normalize(k*k_k) per head; k <- k*(1+(a-1)*k_a) in place ----------------
__global__ __launch_bounds__(256) void kknorm_kernel(
    float* __restrict__ k, const float* __restrict__ a,
    const float* __restrict__ k_k, const float* __restrict__ k_a,
    float* __restrict__ kk)
{
    int row = blockIdx.x;
    int c = threadIdx.x * 8;           // 8 threads per 64-wide head
    size_t base = (size_t)row * C_ + c;
    float kl[8], kkl[8];
    float ss = 0.f;
    #pragma unroll
    for (int j = 0; j < 8; j++) {
        kl[j] = k[base + j];
        float t = kl[j] * k_k[c + j];
        kkl[j] = t;
        ss += t * t;
    }
    ss += __shfl_xor(ss, 1, 64);
    ss += __shfl_xor(ss, 2, 64);
    ss += __shfl_xor(ss, 4, 64);
    float inv = 1.f / fmaxf(sqrtf(ss), 1e-12f);
    #pragma unroll
    for (int j = 0; j < 8; j++) {
        kk[base + j] = kkl[j] * inv;
        float av = a[base + j];
        k[base + j] = kl[j] * (1.f + (av - 1.f) * k_a[c + j]);
    }
}

// ---------------- RWKV-7 scan ----------------
#define SB 16
__global__ __launch_bounds__(256) void scan_kernel(
    const float* __restrict__ rp, const float* __restrict__ dp,
    const float* __restrict__ kp, const float* __restrict__ kkp,
    const float* __restrict__ ap, const float* __restrict__ vp,
    const float* __restrict__ st0, float* __restrict__ xx)
{
    int blk = blockIdx.x;
    int bh = blk >> 2, vblk = blk & 3;
    int b = bh >> 5, h = bh & 31;
    int tid = threadIdx.x;
    int vloc = tid >> 4, kg = tid & 15, c0 = kg * 4;
    int vrow = vblk * 16 + vloc;
    float S0, S1, S2, S3;
    {
        const float* sp = st0 + ((size_t)bh * 64 + vrow) * 64 + c0;
        S0 = sp[0]; S1 = sp[1]; S2 = sp[2]; S3 = sp[3];
    }
    __shared__ float Rs[SB][64], Ds[SB][64], Ks[SB][64], KKs[SB][64], As[SB][64], Vs[SB][64];
    int sidx = (tid * 4) >> 6;
    int nidx = (tid * 4) & 63;
    for (int t0 = 0; t0 < T_; t0 += SB) {
        __syncthreads();
        size_t g = ((size_t)b * T_ + t0 + sidx) * C_ + h * 64 + nidx;
        *(float4*)&Rs[sidx][nidx]  = *(const float4*)&rp[g];
        *(float4*)&Ds[sidx][nidx]  = *(const float4*)&dp[g];
        *(float4*)&Ks[sidx][nidx]  = *(const float4*)&kp[g];
        *(float4*)&KKs[sidx][nidx] = *(const float4*)&kkp[g];
        *(float4*)&As[sidx][nidx]  = *(const float4*)&ap[g];
        *(float4*)&Vs[sidx][nidx]  = *(const float4*)&vp[g];
        __syncthreads();
        for (int s = 0; s < SB; s++) {
            float4 dv  = *(const float4*)&Ds[s][c0];
            float4 kv  = *(const float4*)&Ks[s][c0];
            float4 kkv = *(const float4*)&KKs[s][c0];
            float4 av  = *(const float4*)&As[s][c0];
            float4 rv  = *(const float4*)&Rs[s][c0];
            float vt = Vs[s][vrow];
            float sa = -(S0 * kkv.x + S1 * kkv.y + S2 * kkv.z + S3 * kkv.w);
            sa += __shfl_xor(sa, 1, 64);
            sa += __shfl_xor(sa, 2, 64);
            sa += __shfl_xor(sa, 4, 64);
            sa += __shfl_xor(sa, 8, 64);
            S0 = S0 * dv.x + sa * (kkv.x * av.x) + vt * kv.x;
            S1 = S1 * dv.y + sa * (kkv.y * av.y) + vt * kv.y;
            S2 = S2 * dv.z + sa * (kkv.z * av.z) + vt * kv.z;
            S3 = S3 * dv.w + sa * (kkv.w * av.w) + vt * kv.w;
            float o = S0 * rv.x + S1 * rv.y + S2 * rv.z + S3 * rv.w;
            o += __shfl_xor(o, 1, 64);
            o += __shfl_xor(o, 2, 64);
            o += __shfl_xor(o, 4, 64);
            o += __shfl_xor(o, 8, 64);
            if (kg == 0)
                xx[((size_t)b * T_ + t0 + s) * C_ + h * 64 + vrow] = o;
        }
    }
}

// ---------------- bonus + gate: y = (xx + (sum_head r*k*r_k)*v) * g -> bf16 ----------------
__global__ __launch_bounds__(256) void ygate_kernel(
    const float* __restrict__ xx, const float* __restrict__ r,
    const float* __restrict__ k, const float* __restrict__ r_k,
    const float* __restrict__ v, const float* __restrict__ g,
    u16* __restrict__ y)
{
    int row = blockIdx.x;
    int c = threadIdx.x * 8;
    size_t base = (size_t)row * C_ + c;
    float bsum = 0.f;
    #pragma unroll
    for (int j = 0; j < 8; j++) bsum += r[base + j] * k[base + j] * r_k[c + j];
    bsum += __shfl_xor(bsum, 1, 64);
    bsum += __shfl_xor(bsum, 2, 64);
    bsum += __shfl_xor(bsum, 4, 64);
    #pragma unroll
    for (int j = 0; j < 8; j++) {
        float yv = (xx[base + j] + bsum * v[base + j]) * g[base + j];
        y[base + j] = f2bf(yv);
    }
}

extern "C" void kernel_launch(void* const* d_in, const int* in_sizes, int n_in,
                              void* d_out, int out_size, void* d_ws, size_t ws_size,
                              hipStream_t stream)
{
    const float* x      = (const float*)d_in[0];
    const float* x_prev = (const float*)d_in[1];
    const float* state  = (const float*)d_in[2];
    const float* ln1_w  = (const float*)d_in[3];
    const float* ln2_w  = (const float*)d_in[4];
    const float* x_r = (const float*)d_in[5];
    const float* x_w = (const float*)d_in[6];
    const float* x_k = (const float*)d_in[7];
    const float* x_v = (const float*)d_in[8];
    const float* x_a = (const float*)d_in[9];
    const float* x_g = (const float*)d_in[10];
    const float* w0 = (const float*)d_in[11];
    const float* w1 = (const float*)d_in[12];
    const float* w2 = (const float*)d_in[13];
    const float* a0 = (const float*)d_in[14];
    const float* a1 = (const float*)d_in[15];
    const float* a2 = (const float*)d_in[16];
    const float* g1 = (const float*)d_in[17];
    const float* g2 = (const float*)d_in[18];
    const float* k_k = (const float*)d_in[19];
    const float* k_a = (const float*)d_in[20];
    const float* r_k = (const float*)d_in[21];
    const float* Rw = (const float*)d_in[22];
    const float* Kw = (const float*)d_in[23];
    const float* Vw = (const float*)d_in[24];
    const float* Ow = (const float*)d_in[25];
    const float* gate_w = (const float*)d_in[26];
    const float* up_w   = (const float*)d_in[27];
    const float* down_w = (const float*)d_in[28];
    float* out = (float*)d_out;

    const size_t MBc = 1024ull * 1024ull;
    char* ws = (char*)d_ws;
    // --- lifetime-overlapped layout (242 MB total) ---
    u16*  xr_b = (u16*)(ws + 0 * MBc);
    u16*  xw_b = (u16*)(ws + 8 * MBc);
    u16*  xk_b = (u16*)(ws + 16 * MBc);
    u16*  xv_b = (u16*)(ws + 24 * MBc);
    u16*  xa_b = (u16*)(ws + 32 * MBc);
    u16*  xg_b = (u16*)(ws + 40 * MBc);
    float* xn  = (float*)(ws + 48 * MBc);   // dead before rb written
    float* rb  = (float*)(ws + 48 * MBc);
    float* kb  = (float*)(ws + 64 * MBc);
    float* vb  = (float*)(ws + 80 * MBc);
    float* db  = (float*)(ws + 96 * MBc);
    float* ab  = (float*)(ws + 112 * MBc);
    float* gb  = (float*)(ws + 128 * MBc);
    float* kkb = (float*)(ws + 144 * MBc);
    float* xxb = (float*)(ws + 160 * MBc);  // written at scan (step 8)
    u16*  yb   = (u16*)(ws + 176 * MBc);
    float* x2  = (float*)(ws + 184 * MBc);
    u16*  xn2b = (u16*)(ws + 200 * MBc);
    u16*  Rb   = (u16*)(ws + 208 * MBc);
    u16*  Kb   = (u16*)(ws + 216 * MBc);
    u16*  Vb   = (u16*)(ws + 224 * MBc);
    u16*  Owb  = (u16*)(ws + 232 * MBc);
    // late-phase reuse (mix planes + r/k/v/d/a/g/kk are all dead by then):
    u16*  gateb = (u16*)(ws + 0 * MBc);
    u16*  upb   = (u16*)(ws + 32 * MBc);
    u16*  downb = (u16*)(ws + 64 * MBc);
    u16*  gfb   = (u16*)(ws + 96 * MBc);
    u16*  hb    = (u16*)(ws + 128 * MBc);
    u16*  w2T = (u16*)(ws + 240 * MBc);
    u16*  a2T = (u16*)(ws + 240 * MBc + 256 * 1024);
    u16*  g2T = (u16*)(ws + 240 * MBc + 512 * 1024);
    u16*  t1b = (u16*)(ws + 241 * MBc);
    u16*  t2b = (u16*)(ws + 241 * MBc + 256 * 1024);
    u16*  t3b = (u16*)(ws + 241 * MBc + 512 * 1024);
    // early-phase-only (dead by step 8 when xxb is written): transposed small weights
    u16*  w1T = (u16*)(ws + 160 * MBc);                 // 64 x 2048 bf16 (256 KB)
    u16*  a1T = (u16*)(ws + 160 * MBc + 256 * 1024);    // 64 x 2048
    u16*  g1T = (u16*)(ws + 160 * MBc + 512 * 1024);    // 128 x 2048 (512 KB)

    const long cc = (long)C_ * C_;
    const long fc = (long)FFN_ * C_;

    // 1) ln1 + token-shift mixes
    rmsnorm_kernel<<<BT_, 256, 0, stream>>>(x, ln1_w, xn, nullptr, 0);
    mix_kernel<<<BT_, 256, 0, stream>>>(xn, x_prev, x_r, x_w, x_k, x_v, x_a, x_g,
                                        xr_b, xw_b, xk_b, xv_b, xa_b, xg_b);
    // 2) weight conversions (R/K/V/O) + small transposes (both directions)
    cvt_bf16_kernel<<<cc / 1024, 256, 0, stream>>>(Rw, Rb, cc);
    cvt_bf16_kernel<<<cc / 1024, 256, 0, stream>>>(Kw, Kb, cc);
    cvt_bf16_kernel<<<cc / 1024, 256, 0, stream>>>(Vw, Vb, cc);
    cvt_bf16_kernel<<<cc / 1024, 256, 0, stream>>>(Ow, Owb, cc);
    transpose_kernel<<<(64 * C_ + 255) / 256, 256, 0, stream>>>(w2, w2T, 64, C_);
    transpose_kernel<<<(64 * C_ + 255) / 256, 256, 0, stream>>>(a2, a2T, 64, C_);
    transpose_kernel<<<(128 * C_ + 255) / 256, 256, 0, stream>>>(g2, g2T, 128, C_);
    transpose_kernel<<<(64 * C_ + 255) / 256, 256, 0, stream>>>(w1, w1T, C_, 64);
    transpose_kernel<<<(64 * C_ + 255) / 256, 256, 0, stream>>>(a1, a1T, C_, 64);
    transpose_kernel<<<(128 * C_ + 255) / 256, 256, 0, stream>>>(g1, g1T, C_, 128);
    // 3) r/k/v projections
    gemm_kernel<128><<<dim3(16, 16), 256, 0, stream>>>(xr_b, Rb, rb, nullptr, nullptr, nullptr, BT_, C_, C_, 0);
    gemm_kernel<128><<<dim3(16, 16), 256, 0, stream>>>(xk_b, Kb, kb, nullptr, nullptr, nullptr, BT_, C_, C_, 0);
    gemm_kernel<128><<<dim3(16, 16), 256, 0, stream>>>(xv_b, Vb, vb, nullptr, nullptr, nullptr, BT_, C_, C_, 0);
    // 4) decay path: d = exp(-exp(-softplus(-(w0 + tanh(xw@w1)@w2)) - 0.5))
    gemm_kernel<64><<<dim3(1, 16), 256, 0, stream>>>(xw_b, w1T, nullptr, t1b, nullptr, nullptr, BT_, 64, C_, 4);
    gemm_kernel<128><<<dim3(16, 16), 256, 0, stream>>>(t1b, w2T, db, nullptr, nullptr, nullptr, BT_, C_, 64, 0);
    decay_kernel<<<(BT_ * C_) / 256, 256, 0, stream>>>(db, w0);
    // 5) a path: a = sigmoid(a0 + (xa@a1)@a2)
    gemm_kernel<64><<<dim3(1, 16), 256, 0, stream>>>(xa_b, a1T, nullptr, t2b, nullptr, nullptr, BT_, 64, C_, 6);
    gemm_kernel<128><<<dim3(16, 16), 256, 0, stream>>>(t2b, a2T, ab, nullptr, nullptr, nullptr, BT_, C_, 64, 0);
    siga_kernel<<<(BT_ * C_) / 256, 256, 0, stream>>>(ab, a0);
    // 6) g path: g = sigmoid(xg@g1)@g2
    gemm_kernel<64><<<dim3(2, 16), 256, 0, stream>>>(xg_b, g1T, nullptr, t3b, nullptr, nullptr, BT_, 128, C_, 5);
    gemm_kernel<128><<<dim3(16, 16), 256, 0, stream>>>(t3b, g2T, gb, nullptr, nullptr, nullptr, BT_, C_, 128, 0);
    // 7) kk normalize + k adjust
    kknorm_kernel<<<BT_, 256, 0, stream>>>(kb, ab, k_k, k_a, kkb);
    // 8) RWKV-7 scan
    scan_kernel<<<256, 256, 0, stream>>>(rb, db, kb, kkb, ab, vb, state, xxb);
    // 9) bonus + gate, O-proj with fused residual: x2 = x + ((xx+bonus)*g)@O^T
    ygate_kernel<<<BT_, 256, 0, stream>>>(xxb, rb, kb, r_k, vb, gb, yb);
    gemm_kernel<128><<<dim3(16, 16), 256, 0, stream>>>(yb, Owb, x2, nullptr, x, nullptr, BT_, C_, C_, 3);
    // 10) MLP weights (regions now free), ln2, SwiGLU MLP with fused residual into d_out
    cvt_bf16_kernel<<<fc / 1024, 256, 0, stream>>>(gate_w, gateb, fc);
    cvt_bf16_kernel<<<fc / 1024, 256, 0, stream>>>(up_w, upb, fc);
    cvt_bf16_kernel<<<fc / 1024, 256, 0, stream>>>(down_w, downb, fc);
    rmsnorm_kernel<<<BT_, 256, 0, stream>>>(x2, ln2_w, nullptr, xn2b, 1);
    gemm_kernel<128><<<dim3(64, 16), 256, 0, stream>>>(xn2b, gateb, nullptr, gfb, nullptr, nullptr, BT_, FFN_, C_, 2);
    gemm_kernel<128><<<dim3(64, 16), 256, 0, stream>>>(xn2b, upb, nullptr, hb, nullptr, gfb, BT_, FFN_, C_, 1);
    gemm_kernel<128><<<dim3(16, 16), 256, 0, stream>>>(hb, downb, out, nullptr, x2, nullptr, BT_, C_, FFN_, 3);
}

// Round 3
// 1500.289 us; speedup vs baseline: 1.7207x; 1.0691x over previous
//
#include <hip/hip_runtime.h>
#include <hip/hip_bf16.h>
#include <stdint.h>

// ARWKV-7 forward, MI355X. Round 2:
//  - scan: critical path shortened (kr/br precompute, interleaved dual reduction,
//    register double-buffered staging)
//  - GEMM: m97-style async global_load_lds (width=16) staging, unpadded LDS tiles

#define B_   2
#define T_   1024
#define C_   2048
#define H_   32
#define BT_  (B_*T_)
#define FFN_ 8192

typedef unsigned short u16;
typedef __bf16 bf16x8 __attribute__((ext_vector_type(8)));
typedef u16 ushx8 __attribute__((ext_vector_type(8)));
typedef float floatx4 __attribute__((ext_vector_type(4)));

__device__ __forceinline__ float bf2f(u16 v) {
    unsigned int u = ((unsigned int)v) << 16;
    return __builtin_bit_cast(float, u);
}
__device__ __forceinline__ u16 f2bf(float f) {
    unsigned int u = __builtin_bit_cast(unsigned int, f);
    unsigned int lsb = (u >> 16) & 1u;
    u += 0x7fffu + lsb;                 // round-to-nearest-even
    return (u16)(u >> 16);
}

__device__ __forceinline__ void async_copy16(const u16* g, u16* lds) {
    __builtin_amdgcn_global_load_lds(
        (const __attribute__((address_space(1))) unsigned int*)g,
        (__attribute__((address_space(3))) unsigned int*)lds, 16, 0, 0);
}

// ---------------- rmsnorm (out f32 or bf16) ----------------
__global__ __launch_bounds__(256) void rmsnorm_kernel(
    const float* __restrict__ in, const float* __restrict__ wgt,
    float* __restrict__ outf, u16* __restrict__ outb, int bf)
{
    int row = blockIdx.x;
    int tid = threadIdx.x;
    const float* xp = in + (size_t)row * C_;
    int c = tid * 8;
    float4 v0 = *(const float4*)&xp[c];
    float4 v1 = *(const float4*)&xp[c + 4];
    float ss = v0.x*v0.x + v0.y*v0.y + v0.z*v0.z + v0.w*v0.w
             + v1.x*v1.x + v1.y*v1.y + v1.z*v1.z + v1.w*v1.w;
    #pragma unroll
    for (int m = 1; m < 64; m <<= 1) ss += __shfl_xor(ss, m, 64);
    __shared__ float red[4];
    if ((tid & 63) == 0) red[tid >> 6] = ss;
    __syncthreads();
    ss = red[0] + red[1] + red[2] + red[3];
    float scale = 1.0f / sqrtf(ss / (float)C_ + 1e-6f);
    float vals[8] = {v0.x, v0.y, v0.z, v0.w, v1.x, v1.y, v1.z, v1.w};
    size_t base = (size_t)row * C_ + c;
    if (bf) {
        #pragma unroll
        for (int j = 0; j < 8; j++) outb[base + j] = f2bf(wgt[c + j] * vals[j] * scale);
    } else {
        #pragma unroll
        for (int j = 0; j < 8; j++) outf[base + j] = wgt[c + j] * vals[j] * scale;
    }
}

// ---------------- token-shift mix: 6 bf16 outputs ----------------
__global__ __launch_bounds__(256) void mix_kernel(
    const float* __restrict__ xn, const float* __restrict__ x_prev,
    const float* __restrict__ mr, const float* __restrict__ mw,
    const float* __restrict__ mk, const float* __restrict__ mv,
    const float* __restrict__ ma, const float* __restrict__ mg,
    u16* __restrict__ oxr, u16* __restrict__ oxw, u16* __restrict__ oxk,
    u16* __restrict__ oxv, u16* __restrict__ oxa, u16* __restrict__ oxg)
{
    int row = blockIdx.x;
    int b = row / T_;
    int t = row - b * T_;
    int c = threadIdx.x * 8;
    size_t base = (size_t)row * C_ + c;
    const float* prev = (t == 0) ? (x_prev + (size_t)b * C_ + c) : (xn + base - C_);
    #pragma unroll
    for (int j = 0; j < 8; j++) {
        float xc = xn[base + j];
        float sx = prev[j] - xc;
        int cc = c + j;
        oxr[base + j] = f2bf(xc + sx * mr[cc]);
        oxw[base + j] = f2bf(xc + sx * mw[cc]);
        oxk[base + j] = f2bf(xc + sx * mk[cc]);
        oxv[base + j] = f2bf(xc + sx * mv[cc]);
        oxa[base + j] = f2bf(xc + sx * ma[cc]);
        oxg[base + j] = f2bf(xc + sx * mg[cc]);
    }
}

// ---------------- f32 -> bf16 convert ----------------
__global__ __launch_bounds__(256) void cvt_bf16_kernel(
    const float* __restrict__ in, u16* __restrict__ out, long n)
{
    long i = ((long)blockIdx.x * 256 + threadIdx.x) * 4;
    if (i + 3 >= n) return;
    float4 v = *(const float4*)&in[i];
    out[i]     = f2bf(v.x);
    out[i + 1] = f2bf(v.y);
    out[i + 2] = f2bf(v.z);
    out[i + 3] = f2bf(v.w);
}

// ---------------- transpose [rows_in, cols_in] f32 -> [cols_in, rows_in] bf16 ----------------
__global__ __launch_bounds__(256) void transpose_kernel(
    const float* __restrict__ in, u16* __restrict__ out, int rows_in, int cols_in)
{
    long idx = (long)blockIdx.x * 256 + threadIdx.x;
    long total = (long)rows_in * cols_in;
    if (idx >= total) return;
    long o = idx / rows_in;
    long i = idx - o * rows_in;
    out[idx] = f2bf(in[i * (long)cols_in + o]);
}

// ---------------- main MFMA GEMM: C[M,N] = A[M,K]bf16 @ W[N,K]bf16^T ----------------
// BMxBN tile (BM=128, BN=128 or 64), BK=32, 4 waves (2x2), wave computes
// 4 x (BN/32) tiles of mfma_f32_16x16x32_bf16. Staging: async global_load_lds
// width=16, unpadded [rows][32]-u16 LDS tiles (lane order matches LDS layout).
// Epilogue modes: 0: Cf=acc; 1: Cb=bf16(acc*bf2f(Ob[idx])); 2: Cb=bf16(silu(acc));
//   3: Cf=acc+Of[idx]; 4: Cb=bf16(tanh(acc)); 5: Cb=bf16(sigmoid(acc)); 6: Cb=bf16(acc).
template<int BN>
__global__ __launch_bounds__(256, 2) void gemm_kernel(
    const u16* __restrict__ A, const u16* __restrict__ W,
    float* __restrict__ Cf, u16* __restrict__ Cb,
    const float* __restrict__ Of, const u16* __restrict__ Ob,
    int M, int N, int K, int mode)
{
    constexpr int IN = BN / 32;        // tiles per wave in N: 4 (BN=128) or 2 (BN=64)
    __shared__ u16 As[128 * 32];
    __shared__ u16 Ws[BN * 32];
    const int tid = threadIdx.x;
    const int bm = blockIdx.y, bn = blockIdx.x;
    const int row0 = bm * 128, col0 = bn * BN;
    const int wave = tid >> 6, lane = tid & 63;
    const int wr = wave >> 1, wc = wave & 1;
    const int q = lane >> 4, l16 = lane & 15;
    const int lr = lane >> 2;          // 0..15 (row within 16-row slab)
    const int lc = (lane & 3) * 8;     // u16 col chunk

    floatx4 acc[4][IN];
    #pragma unroll
    for (int i = 0; i < 4; i++)
        #pragma unroll
        for (int j = 0; j < IN; j++) acc[i][j] = (floatx4){0.f, 0.f, 0.f, 0.f};

    for (int k0 = 0; k0 < K; k0 += 32) {
        __syncthreads();               // previous iter's ds_reads complete
        // A: 128 rows x 32 k. Each wave stages 32 rows (2 insts x 16 rows x 64B).
        #pragma unroll
        for (int j = 0; j < 2; j++) {
            int r = wave * 32 + j * 16;
            async_copy16(&A[(size_t)(row0 + r + lr) * K + k0 + lc], &As[r * 32]);
        }
        if (BN == 128) {
            #pragma unroll
            for (int j = 0; j < 2; j++) {
                int r = wave * 32 + j * 16;
                async_copy16(&W[(size_t)(col0 + r + lr) * K + k0 + lc], &Ws[r * 32]);
            }
        } else {
            int r = wave * 16;
            async_copy16(&W[(size_t)(col0 + r + lr) * K + k0 + lc], &Ws[r * 32]);
        }
        __syncthreads();               // compiler emits vmcnt(0) drain before barrier
        bf16x8 af[4], wf[IN];
        #pragma unroll
        for (int im = 0; im < 4; im++) {
            int r = wr * 64 + im * 16 + l16;
            af[im] = __builtin_bit_cast(bf16x8, *(const ushx8*)&As[r * 32 + q * 8]);
        }
        #pragma unroll
        for (int in_ = 0; in_ < IN; in_++) {
            int r = wc * (BN / 2) + in_ * 16 + l16;
            wf[in_] = __builtin_bit_cast(bf16x8, *(const ushx8*)&Ws[r * 32 + q * 8]);
        }
        #pragma unroll
        for (int im = 0; im < 4; im++)
            #pragma unroll
            for (int in_ = 0; in_ < IN; in_++)
                acc[im][in_] = __builtin_amdgcn_mfma_f32_16x16x32_bf16(
                    af[im], wf[in_], acc[im][in_], 0, 0, 0);
    }

    #pragma unroll
    for (int im = 0; im < 4; im++) {
        #pragma unroll
        for (int in_ = 0; in_ < IN; in_++) {
            #pragma unroll
            for (int rg = 0; rg < 4; rg++) {
                int row = row0 + wr * 64 + im * 16 + q * 4 + rg;
                int col = col0 + wc * (BN / 2) + in_ * 16 + l16;
                if (row < M && col < N) {
                    size_t idx = (size_t)row * N + col;
                    float v = acc[im][in_][rg];
                    switch (mode) {
                        case 0: Cf[idx] = v; break;
                        case 1: Cb[idx] = f2bf(v * bf2f(Ob[idx])); break;
                        case 2: { float s = v / (1.f + expf(-v)); Cb[idx] = f2bf(s); } break;
                        case 3: Cf[idx] = v + Of[idx]; break;
                        case 4: Cb[idx] = f2bf(tanhf(v)); break;
                        case 5: Cb[idx] = f2bf(1.f / (1.f + expf(-v))); break;
                        case 6: Cb[idx] = f2bf(v); break;
                    }
                }
            }
        }
    }
}

// ---------------- decay: d = exp(-exp(-softplus(-(w0+z)) - 0.5)), in place ----------------
__global__ __launch_bounds__(256) void decay_kernel(
    float* __restrict__ z, const float* __restrict__ w0)
{
    long i = (long)blockIdx.x * 256 + threadIdx.x;
    int c = (int)(i & (C_ - 1));
    float zp = w0[c] + z[i];
    float xneg = -zp;
    float sp = (xneg > 20.f) ? xneg : log1pf(expf(xneg));
    float wpre = -sp - 0.5f;
    z[i] = expf(-expf(wpre));
}

// ---------------- a = sigmoid(a0 + z), in place ----------------
__global__ __launch_bounds__(256) void siga_kernel(
    float* __restrict__ z, const float* __restrict__ a0)
{
    long i = (long)blockIdx.x * 256 + threadIdx.x;
    int c = (int)(i & (C_ - 1));
    z[i] = 1.f / (1.f + expf(-(a0[c] + z[i])));
}

// ---------------- kknorm + per-head scalars kr = k.r, br = (kk*a).r ----------------
// kk = normalize(k*k_k) per head; k <- k*(1+(a-1)*k_a) in place; kr/br -> [BT,H]
__global__ __launch_bounds__(256) void kknorm_kernel(
    float* __restrict__ k, const float* __restrict__ a,
    const float* __restrict__ k_k, const float* __restrict__ k_a,
    const float* __restrict__ r, float* __restrict__ kk,
    float* __restrict__ kr, float* __restrict__ br)
{
    int row = blockIdx.x;
    int tid = threadIdx.x;
    int c = tid * 8;                   // 8 threads per 64-wide head
    int h = tid >> 3, j8 = tid & 7;
    size_t base = (size_t)row * C_ + c;
    float kl[8], kkl[8], al[8];
    float ss = 0.f;
    #pragma unroll
    for (int j = 0; j < 8; j++) {
        kl[j] = k[base + j];
        al[j] = a[base + j];
        float t = kl[j] * k_k[c + j];
        kkl[j] = t;
        ss += t * t;
    }
    ss += __shfl_xor(ss, 1, 64);
    ss += __shfl_xor(ss, 2, 64);
    ss += __shfl_xor(ss, 4, 64);
    float inv = 1.f / fmaxf(sqrtf(ss), 1e-12f);
    float krp = 0.f, brp = 0.f;
    #pragma unroll
    for (int j = 0; j < 8; j++) {
        float kkv = kkl[j] * inv;
        kk[base + j] = kkv;
        float knew = kl[j] * (1.f + (al[j] - 1.f) * k_a[c + j]);
        k[base + j] = knew;
        float rv = r[base + j];
        krp += knew * rv;
        brp += kkv * al[j] * rv;
    }
    krp += __shfl_xor(krp, 1, 64); brp += __shfl_xor(brp, 1, 64);
    krp += __shfl_xor(krp, 2, 64); brp += __shfl_xor(brp, 2, 64);
    krp += __shfl_xor(krp, 4, 64); brp += __shfl_xor(brp, 4, 64);
    if (j8 == 0) {
        kr[(size_t)row * H_ + h] = krp;
        br[(size_t)row * H_ + h] = brp;
    }
}

// ---------------- RWKV-7 scan ----------------
// Per step: sa = S.(-kk) and rd = S.(d*r) reduce concurrently (interleaved shfl);
// o = rd + sa*br + v*kr uses precomputed per-head kr/br; next-state chain after
// sa is a single FMA (base = S*d + v*k precomputed).
#define SB 16
__global__ __launch_bounds__(256) void scan_kernel(
    const float* __restrict__ rp, const float* __restrict__ dp,
    const float* __restrict__ kp, const float* __restrict__ kkp,
    const float* __restrict__ ap, const float* __restrict__ vp,
    const float* __restrict__ krp, const float* __restrict__ brp,
    const float* __restrict__ st0, float* __restrict__ xx)
{
    int blk = blockIdx.x;
    int bh = blk >> 2, vblk = blk & 3;
    int b = bh >> 5, h = bh & 31;
    int tid = threadIdx.x;
    int vloc = tid >> 4, kg = tid & 15, c0 = kg * 4;
    int vrow = vblk * 16 + vloc;
    float S0, S1, S2, S3;
    {
        const float* sp = st0 + ((size_t)bh * 64 + vrow) * 64 + c0;
        S0 = sp[0]; S1 = sp[1]; S2 = sp[2]; S3 = sp[3];
    }
    __shared__ float Rs[SB][64], Ds[SB][64], Ks[SB][64], KKs[SB][64], As[SB][64], Vs[SB][64];
    __shared__ float KRs[SB], BRs[SB];
    int sidx = (tid * 4) >> 6;
    int nidx = (tid * 4) & 63;
    size_t gstep = (size_t)(b * T_) * C_ + h * 64 + nidx;

    float4 pr, pd, pk, pkk, pa, pv;
    float pkr = 0.f, pbr = 0.f;
    {
        size_t g = gstep + (size_t)sidx * C_;
        pr  = *(const float4*)&rp[g];
        pd  = *(const float4*)&dp[g];
        pk  = *(const float4*)&kp[g];
        pkk = *(const float4*)&kkp[g];
        pa  = *(const float4*)&ap[g];
        pv  = *(const float4*)&vp[g];
        if (tid < SB) {
            pkr = krp[(size_t)(b * T_ + tid) * H_ + h];
            pbr = brp[(size_t)(b * T_ + tid) * H_ + h];
        }
    }

    for (int t0 = 0; t0 < T_; t0 += SB) {
        *(float4*)&Rs[sidx][nidx]  = pr;
        *(float4*)&Ds[sidx][nidx]  = pd;
        *(float4*)&Ks[sidx][nidx]  = pk;
        *(float4*)&KKs[sidx][nidx] = pkk;
        *(float4*)&As[sidx][nidx]  = pa;
        *(float4*)&Vs[sidx][nidx]  = pv;
        if (tid < SB) { KRs[tid] = pkr; BRs[tid] = pbr; }
        __syncthreads();
        if (t0 + SB < T_) {
            size_t g = gstep + (size_t)(t0 + SB + sidx) * C_;
            pr  = *(const float4*)&rp[g];
            pd  = *(const float4*)&dp[g];
            pk  = *(const float4*)&kp[g];
            pkk = *(const float4*)&kkp[g];
            pa  = *(const float4*)&ap[g];
            pv  = *(const float4*)&vp[g];
            if (tid < SB) {
                pkr = krp[(size_t)(b * T_ + t0 + SB + tid) * H_ + h];
                pbr = brp[(size_t)(b * T_ + t0 + SB + tid) * H_ + h];
            }
        }
        #pragma unroll 4
        for (int s = 0; s < SB; s++) {
            float4 dv  = *(const float4*)&Ds[s][c0];
            float4 kv  = *(const float4*)&Ks[s][c0];
            float4 kkv = *(const float4*)&KKs[s][c0];
            float4 av  = *(const float4*)&As[s][c0];
            float4 rv  = *(const float4*)&Rs[s][c0];
            float vt = Vs[s][vrow];
            float krt = KRs[s], brt = BRs[s];
            // two independent reductions on S_{t-1}
            float sa = -((S0 * kkv.x + S1 * kkv.y) + (S2 * kkv.z + S3 * kkv.w));
            float rd = (S0 * (dv.x * rv.x) + S1 * (dv.y * rv.y))
                     + (S2 * (dv.z * rv.z) + S3 * (dv.w * rv.w));
            // off-critical-path precompute while shfls are in flight:
            float bx = kkv.x * av.x, by = kkv.y * av.y, bz = kkv.z * av.z, bw = kkv.w * av.w;
            float base0 = fmaf(S0, dv.x, vt * kv.x);
            float base1 = fmaf(S1, dv.y, vt * kv.y);
            float base2 = fmaf(S2, dv.z, vt * kv.z);
            float base3 = fmaf(S3, dv.w, vt * kv.w);
            sa += __shfl_xor(sa, 1, 64); rd += __shfl_xor(rd, 1, 64);
            sa += __shfl_xor(sa, 2, 64); rd += __shfl_xor(rd, 2, 64);
            sa += __shfl_xor(sa, 4, 64); rd += __shfl_xor(rd, 4, 64);
            sa += __shfl_xor(sa, 8, 64); rd += __shfl_xor(rd, 8, 64);
            S0 = fmaf(sa, bx, base0);
            S1 = fmaf(sa, by, base1);
            S2 = fmaf(sa, bz, base2);
            S3 = fmaf(sa, bw, base3);
            if (kg == 0) {
                float o = fmaf(sa, brt, rd);
                o = fmaf(vt, krt, o);
                xx[((size_t)b * T_ + t0 + s) * C_ + h * 64 + vrow] = o;
            }
        }
        __syncthreads();
    }
}

// ---------------- bonus + gate: y = (xx + (sum_head r*k*r_k)*v) * g -> bf16 ----------------
__global__ __launch_bounds__(256) void ygate_kernel(
    const float* __restrict__ xx, const float* __restrict__ r,
    const float* __restrict__ k, const float* __restrict__ r_k,
    const float* __restrict__ v, const float* __restrict__ g,
    u16* __restrict__ y)
{
    int row = blockIdx.x;
    int c = threadIdx.x * 8;
    size_t base = (size_t)row * C_ + c;
    float bsum = 0.f;
    #pragma unroll
    for (int j = 0; j < 8; j++) bsum += r[base + j] * k[base + j] * r_k[c + j];
    bsum += __shfl_xor(bsum, 1, 64);
    bsum += __shfl_xor(bsum, 2, 64);
    bsum += __shfl_xor(bsum, 4, 64);
    #pragma unroll
    for (int j = 0; j < 8; j++) {
        float yv = (xx[base + j] + bsum * v[base + j]) * g[base + j];
        y[base + j] = f2bf(yv);
    }
}

extern "C" void kernel_launch(void* const* d_in, const int* in_sizes, int n_in,
                              void* d_out, int out_size, void* d_ws, size_t ws_size,
                              hipStream_t stream)
{
    const float* x      = (const float*)d_in[0];
    const float* x_prev = (const float*)d_in[1];
    const float* state  = (const float*)d_in[2];
    const float* ln1_w  = (const float*)d_in[3];
    const float* ln2_w  = (const float*)d_in[4];
    const float* x_r = (const float*)d_in[5];
    const float* x_w = (const float*)d_in[6];
    const float* x_k = (const float*)d_in[7];
    const float* x_v = (const float*)d_in[8];
    const float* x_a = (const float*)d_in[9];
    const float* x_g = (const float*)d_in[10];
    const float* w0 = (const float*)d_in[11];
    const float* w1 = (const float*)d_in[12];
    const float* w2 = (const float*)d_in[13];
    const float* a0 = (const float*)d_in[14];
    const float* a1 = (const float*)d_in[15];
    const float* a2 = (const float*)d_in[16];
    const float* g1 = (const float*)d_in[17];
    const float* g2 = (const float*)d_in[18];
    const float* k_k = (const float*)d_in[19];
    const float* k_a = (const float*)d_in[20];
    const float* r_k = (const float*)d_in[21];
    const float* Rw = (const float*)d_in[22];
    const float* Kw = (const float*)d_in[23];
    const float* Vw = (const float*)d_in[24];
    const float* Ow = (const float*)d_in[25];
    const float* gate_w = (const float*)d_in[26];
    const float* up_w   = (const float*)d_in[27];
    const float* down_w = (const float*)d_in[28];
    float* out = (float*)d_out;

    const size_t MBc = 1024ull * 1024ull;
    char* ws = (char*)d_ws;
    // --- lifetime-overlapped layout (242 MB total) ---
    u16*  xr_b = (u16*)(ws + 0 * MBc);
    u16*  xw_b = (u16*)(ws + 8 * MBc);
    u16*  xk_b = (u16*)(ws + 16 * MBc);
    u16*  xv_b = (u16*)(ws + 24 * MBc);
    u16*  xa_b = (u16*)(ws + 32 * MBc);
    u16*  xg_b = (u16*)(ws + 40 * MBc);
    float* xn  = (float*)(ws + 48 * MBc);   // dead before rb written
    float* rb  = (float*)(ws + 48 * MBc);
    float* kb  = (float*)(ws + 64 * MBc);
    float* vb  = (float*)(ws + 80 * MBc);
    float* db  = (float*)(ws + 96 * MBc);
    float* ab  = (float*)(ws + 112 * MBc);
    float* gb  = (float*)(ws + 128 * MBc);
    float* kkb = (float*)(ws + 144 * MBc);
    float* xxb = (float*)(ws + 160 * MBc);  // written at scan (step 8)
    u16*  yb   = (u16*)(ws + 176 * MBc);    // written at step 9 (after scan)
    float* x2  = (float*)(ws + 184 * MBc);
    u16*  xn2b = (u16*)(ws + 200 * MBc);
    u16*  Rb   = (u16*)(ws + 208 * MBc);
    u16*  Kb   = (u16*)(ws + 216 * MBc);
    u16*  Vb   = (u16*)(ws + 224 * MBc);
    u16*  Owb  = (u16*)(ws + 232 * MBc);
    // late-phase reuse (mix planes + r/k/v/d/a/g/kk are all dead by then):
    u16*  gateb = (u16*)(ws + 0 * MBc);
    u16*  upb   = (u16*)(ws + 32 * MBc);
    u16*  downb = (u16*)(ws + 64 * MBc);
    u16*  gfb   = (u16*)(ws + 96 * MBc);
    u16*  hb    = (u16*)(ws + 128 * MBc);
    u16*  w2T = (u16*)(ws + 240 * MBc);
    u16*  a2T = (u16*)(ws + 240 * MBc + 256 * 1024);
    u16*  g2T = (u16*)(ws + 240 * MBc + 512 * 1024);
    u16*  t1b = (u16*)(ws + 241 * MBc);
    u16*  t2b = (u16*)(ws + 241 * MBc + 256 * 1024);
    u16*  t3b = (u16*)(ws + 241 * MBc + 512 * 1024);
    // early-phase-only (dead by step 8 when xxb is written): transposed small weights
    u16*  w1T = (u16*)(ws + 160 * MBc);                 // 64 x 2048 bf16 (256 KB)
    u16*  a1T = (u16*)(ws + 160 * MBc + 256 * 1024);    // 64 x 2048
    u16*  g1T = (u16*)(ws + 160 * MBc + 512 * 1024);    // 128 x 2048 (512 KB)
    // kr/br [BT,H] f32 (256 KB each): live steps 7-8 only; yb region is free then
    float* krb = (float*)(ws + 176 * MBc);
    float* brb = (float*)(ws + 176 * MBc + 256 * 1024);

    const long cc = (long)C_ * C_;
    const long fc = (long)FFN_ * C_;

    // 1) ln1 + token-shift mixes
    rmsnorm_kernel<<<BT_, 256, 0, stream>>>(x, ln1_w, xn, nullptr, 0);
    mix_kernel<<<BT_, 256, 0, stream>>>(xn, x_prev, x_r, x_w, x_k, x_v, x_a, x_g,
                                        xr_b, xw_b, xk_b, xv_b, xa_b, xg_b);
    // 2) weight conversions (R/K/V/O) + small transposes (both directions)
    cvt_bf16_kernel<<<cc / 1024, 256, 0, stream>>>(Rw, Rb, cc);
    cvt_bf16_kernel<<<cc / 1024, 256, 0, stream>>>(Kw, Kb, cc);
    cvt_bf16_kernel<<<cc / 1024, 256, 0, stream>>>(Vw, Vb, cc);
    cvt_bf16_kernel<<<cc / 1024, 256, 0, stream>>>(Ow, Owb, cc);
    transpose_kernel<<<(64 * C_ + 255) / 256, 256, 0, stream>>>(w2, w2T, 64, C_);
    transpose_kernel<<<(64 * C_ + 255) / 256, 256, 0, stream>>>(a2, a2T, 64, C_);
    transpose_kernel<<<(128 * C_ + 255) / 256, 256, 0, stream>>>(g2, g2T, 128, C_);
    transpose_kernel<<<(64 * C_ + 255) / 256, 256, 0, stream>>>(w1, w1T, C_, 64);
    transpose_kernel<<<(64 * C_ + 255) / 256, 256, 0, stream>>>(a1, a1T, C_, 64);
    transpose_kernel<<<(128 * C_ + 255) / 256, 256, 0, stream>>>(g1, g1T, C_, 128);
    // 3) r/k/v projections
    gemm_kernel<128><<<dim3(16, 16), 256, 0, stream>>>(xr_b, Rb, rb, nullptr, nullptr, nullptr, BT_, C_, C_, 0);
    gemm_kernel<128><<<dim3(16, 16), 256, 0, stream>>>(xk_b, Kb, kb, nullptr, nullptr, nullptr, BT_, C_, C_, 0);
    gemm_kernel<128><<<dim3(16, 16), 256, 0, stream>>>(xv_b, Vb, vb, nullptr, nullptr, nullptr, BT_, C_, C_, 0);
    // 4) decay path: d = exp(-exp(-softplus(-(w0 + tanh(xw@w1)@w2)) - 0.5))
    gemm_kernel<64><<<dim3(1, 16), 256, 0, stream>>>(xw_b, w1T, nullptr, t1b, nullptr, nullptr, BT_, 64, C_, 4);
    gemm_kernel<128><<<dim3(16, 16), 256, 0, stream>>>(t1b, w2T, db, nullptr, nullptr, nullptr, BT_, C_, 64, 0);
    decay_kernel<<<(BT_ * C_) / 256, 256, 0, stream>>>(db, w0);
    // 5) a path: a = sigmoid(a0 + (xa@a1)@a2)
    gemm_kernel<64><<<dim3(1, 16), 256, 0, stream>>>(xa_b, a1T, nullptr, t2b, nullptr, nullptr, BT_, 64, C_, 6);
    gemm_kernel<128><<<dim3(16, 16), 256, 0, stream>>>(t2b, a2T, ab, nullptr, nullptr, nullptr, BT_, C_, 64, 0);
    siga_kernel<<<(BT_ * C_) / 256, 256, 0, stream>>>(ab, a0);
    // 6) g path: g = sigmoid(xg@g1)@g2
    gemm_kernel<64><<<dim3(2, 16), 256, 0, stream>>>(xg_b, g1T, nullptr, t3b, nullptr, nullptr, BT_, 128, C_, 5);
    gemm_kernel<128><<<dim3(16, 16), 256, 0, stream>>>(t3b, g2T, gb, nullptr, nullptr, nullptr, BT_, C_, 128, 0);
    // 7) kk normalize + k adjust + kr/br per-head scalars
    kknorm_kernel<<<BT_, 256, 0, stream>>>(kb, ab, k_k, k_a, rb, kkb, krb, brb);
    // 8) RWKV-7 scan
    scan_kernel<<<256, 256, 0, stream>>>(rb, db, kb, kkb, ab, vb, krb, brb, state, xxb);
    // 9) bonus + gate, O-proj with fused residual: x2 = x + ((xx+bonus)*g)@O^T
    ygate_kernel<<<BT_, 256, 0, stream>>>(xxb, rb, kb, r_k, vb, gb, yb);
    gemm_kernel<128><<<dim3(16, 16), 256, 0, stream>>>(yb, Owb, x2, nullptr, x, nullptr, BT_, C_, C_, 3);
    // 10) MLP weights (regions now free), ln2, SwiGLU MLP with fused residual into d_out
    cvt_bf16_kernel<<<fc / 1024, 256, 0, stream>>>(gate_w, gateb, fc);
    cvt_bf16_kernel<<<fc / 1024, 256, 0, stream>>>(up_w, upb, fc);
    cvt_bf16_kernel<<<fc / 1024, 256, 0, stream>>>(down_w, downb, fc);
    rmsnorm_kernel<<<BT_, 256, 0, stream>>>(x2, ln2_w, nullptr, xn2b, 1);
    gemm_kernel<128><<<dim3(64, 16), 256, 0, stream>>>(xn2b, gateb, nullptr, gfb, nullptr, nullptr, BT_, FFN_, C_, 2);
    gemm_kernel<128><<<dim3(64, 16), 256, 0, stream>>>(xn2b, upb, nullptr, hb, nullptr, gfb, BT_, FFN_, C_, 1);
    gemm_kernel<128><<<dim3(16, 16), 256, 0, stream>>>(hb, downb, out, nullptr, x2, nullptr, BT_, C_, FFN_, 3);
}